// Round 1
// 656.804 us; speedup vs baseline: 1.0079x; 1.0079x over previous
//
#include <hip/hip_runtime.h>
#include <hip/hip_bf16.h>

// GraphSAGE 3-layer, N=50000 nodes, E=400000 edges, dims 512->512->512->128.
// Round 8 -> 9:
//  GEMM staging moved from reg-round-trip (global->VGPR->ds_write) to
//  __builtin_amdgcn_global_load_lds width=16 (m97 structure). LDS dest is
//  lane-linear (HW requirement, m104); the XOR bank swizzle is applied to the
//  GLOBAL source address instead (rule 21: linear dest + inverse-swz source +
//  swz on read). One barrier per K-step; loads for it+1 issued before the
//  MFMAs of it, drained by the end-of-iter barrier. Removes the per-iter
//  vmcnt-wait + ds_write latency from the critical path (m151: 646->874 TF
//  for exactly this tile structure).

#define N_NODES 50000
#define N_EDGES 400000

typedef unsigned short u16;
typedef unsigned int u32;
typedef __attribute__((ext_vector_type(8))) short short8;
typedef __attribute__((ext_vector_type(4))) float floatx4;

#define ASYNC16(g, l)                                                      \
    __builtin_amdgcn_global_load_lds(                                      \
        (const __attribute__((address_space(1))) void*)(g),                \
        (__attribute__((address_space(3))) void*)(l), 16, 0, 0)

__device__ __forceinline__ u16 f32_to_bf16(float f) {
    u32 u = __float_as_uint(f);
    u32 r = 0x7FFFu + ((u >> 16) & 1u);
    return (u16)((u + r) >> 16);
}
__device__ __forceinline__ float bf16_to_f32(u32 lo16) {
    return __uint_as_float(lo16 << 16);
}

__global__ __launch_bounds__(256) void zero4_kernel(float4* __restrict__ p, int n4) {
    int i = blockIdx.x * 256 + threadIdx.x;
    if (i < n4) p[i] = make_float4(0.f, 0.f, 0.f, 0.f);
}

__global__ __launch_bounds__(256) void hist_kernel(const int* __restrict__ dst,
                                                   int* __restrict__ deg, int E) {
    int e = blockIdx.x * 256 + threadIdx.x;
    if (e < E) atomicAdd(&deg[dst[e]], 1);
}

__global__ __launch_bounds__(256) void scan_reduce(const int* __restrict__ v,
                                                   int* __restrict__ bsums, int n) {
    __shared__ int sh[256];
    int i = blockIdx.x * 256 + threadIdx.x;
    sh[threadIdx.x] = (i < n) ? v[i] : 0;
    __syncthreads();
    for (int off = 128; off > 0; off >>= 1) {
        if (threadIdx.x < off) sh[threadIdx.x] += sh[threadIdx.x + off];
        __syncthreads();
    }
    if (threadIdx.x == 0) bsums[blockIdx.x] = sh[0];
}

__global__ __launch_bounds__(256) void scan_sums(int* __restrict__ bsums, int nb) {
    __shared__ int sh[256];
    int t = threadIdx.x;
    int val = (t < nb) ? bsums[t] : 0;
    sh[t] = val;
    __syncthreads();
    for (int off = 1; off < 256; off <<= 1) {
        int v = (t >= off) ? sh[t - off] : 0;
        __syncthreads();
        sh[t] += v;
        __syncthreads();
    }
    if (t < nb) bsums[t] = sh[t] - val;
}

__global__ __launch_bounds__(256) void scan_final(int* __restrict__ v,
                                                  const int* __restrict__ bsums, int n) {
    __shared__ int sh[256];
    int t = threadIdx.x;
    int i = blockIdx.x * 256 + t;
    int val = (i < n) ? v[i] : 0;
    sh[t] = val;
    __syncthreads();
    for (int off = 1; off < 256; off <<= 1) {
        int x = (t >= off) ? sh[t - off] : 0;
        __syncthreads();
        sh[t] += x;
        __syncthreads();
    }
    int excl = sh[t] - val + bsums[blockIdx.x];
    if (i < n) v[i] = excl;
    if (i == n - 1) v[n] = excl + val;
}

__global__ __launch_bounds__(256) void fill_kernel(const int* __restrict__ src,
                                                   const int* __restrict__ dst,
                                                   const int* __restrict__ row_start,
                                                   int* __restrict__ cursor,
                                                   int* __restrict__ csr_src, int E) {
    int e = blockIdx.x * 256 + threadIdx.x;
    if (e < E) {
        int d = dst[e];
        int pos = row_start[d] + atomicAdd(&cursor[d], 1);
        csr_src[pos] = src[e];
    }
}

// f32 [n8*8] -> bf16, 8 elems/thread
__global__ __launch_bounds__(256) void convert_bf16(const float* __restrict__ in,
                                                    u16* __restrict__ out, int n8) {
    int i = blockIdx.x * 256 + threadIdx.x;
    if (i >= n8) return;
    const float4* p = (const float4*)in + (size_t)i * 2;
    float4 v0 = p[0], v1 = p[1];
    uint4 o;
    o.x = (u32)f32_to_bf16(v0.x) | ((u32)f32_to_bf16(v0.y) << 16);
    o.y = (u32)f32_to_bf16(v0.z) | ((u32)f32_to_bf16(v0.w) << 16);
    o.z = (u32)f32_to_bf16(v1.x) | ((u32)f32_to_bf16(v1.y) << 16);
    o.w = (u32)f32_to_bf16(v1.z) | ((u32)f32_to_bf16(v1.w) << 16);
    ((uint4*)out)[i] = o;
}

// W [K][N] f32 -> WT [N][K] bf16, 32x32 tiles
__global__ __launch_bounds__(256) void transpose_w(const float* __restrict__ W,
                                                   u16* __restrict__ WT,
                                                   int K, int N) {
    __shared__ float t[32][33];
    int n0 = blockIdx.x * 32, k0 = blockIdx.y * 32;
    int c = threadIdx.x & 31, r0 = threadIdx.x >> 5;
    for (int r = r0; r < 32; r += 8)
        t[r][c] = W[(size_t)(k0 + r) * N + n0 + c];
    __syncthreads();
    for (int r = r0; r < 32; r += 8)
        WT[(size_t)(n0 + r) * K + k0 + c] = f32_to_bf16(t[c][r]);
}

// C = A @ BT' (BT stored [N][512], k-contig), single pass K=512, bf16 out.
// 128x128 tile, dbuf LDS, global_load_lds staging (lane-linear dest,
// source-swizzled), 1 barrier/iter, swapped-operand MFMA.
// Output split: cols < split -> Cl (row stride split), else Cr (col-split).
__global__ __launch_bounds__(256) void gemm_bf16(
    const u16* __restrict__ A, const u16* __restrict__ BT,
    u16* __restrict__ Cl, u16* __restrict__ Cr,
    int M, int split, int nStrips, int nCols) {
    __shared__ u16 As[2][4096];  // 128 rows x 32 u16 (64B), lane-linear
    __shared__ u16 Bs[2][4096];

    const int grp = 8 * nCols;
    int b = blockIdx.x;
    int strip = (b / grp) * 8 + (b & 7);   // col-tiles of a strip share b%8 -> XCD
    int colt = (b % grp) >> 3;
    if (strip >= nStrips) return;
    const int row0 = strip * 128, col0 = colt * 128;

    const int t = threadIdx.x;
    const int w = t >> 6, lane = t & 63;
    const int wm = (w >> 1) * 64, wn = (w & 1) * 64;
    const int l15 = lane & 15, kq = lane >> 4;
    const int swz = (l15 >> 1) & 3;        // fragment-read swizzle bits

    floatx4 acc[4][4];
#pragma unroll
    for (int i = 0; i < 4; ++i)
#pragma unroll
        for (int j = 0; j < 4; ++j) acc[i][j] = floatx4{0.f, 0.f, 0.f, 0.f};

    // Staging geometry: thread t -> rows sr, sr+64; 16B chunk sc = t&3.
    // Wave w writes LDS bytes [w*1024, w*1024+1024) (lane-linear, HW req).
    // Bank swizzle lives in the GLOBAL source: position sc receives global
    // chunk sc^swzS; reader fetches logical chunk kq at position kq^swz.
    const int sr = t >> 2;
    const int sc = t & 3;
    const int swzS = (sr >> 1) & 3;        // == (row>>1)&3 for sr and sr+64
    const size_t aA0 = (size_t)min(row0 + sr, M - 1) * 512 + (sc ^ swzS) * 8;
    const size_t aA1 = (size_t)min(row0 + 64 + sr, M - 1) * 512 + (sc ^ swzS) * 8;
    const size_t aB0 = (size_t)(col0 + sr) * 512 + (sc ^ swzS) * 8;
    const size_t aB1 = (size_t)(col0 + 64 + sr) * 512 + (sc ^ swzS) * 8;
    const int d0 = w * 512;        // u16 index: wave-uniform LDS dest, part 0
    const int d1 = 2048 + w * 512; // rows +64

    auto stage = [&](int it, int buf) {
        const int eff = it * 32;
        ASYNC16(A + aA0 + eff, &As[buf][d0]);
        ASYNC16(A + aA1 + eff, &As[buf][d1]);
        ASYNC16(BT + aB0 + eff, &Bs[buf][d0]);
        ASYNC16(BT + aB1 + eff, &Bs[buf][d1]);
    };

    stage(0, 0);
    __syncthreads();  // vmcnt(0) drain: buf0 ready
    for (int it = 0; it < 16; ++it) {
        const int buf = it & 1;
        if (it + 1 < 16) stage(it + 1, buf ^ 1);  // in flight across the MFMAs

        const int kc = (kq ^ swz) * 8;      // swizzled chunk for this lane
        short8 a[4], bfr[4];
#pragma unroll
        for (int mt = 0; mt < 4; ++mt)
            a[mt] = *(const short8*)&As[buf][(wm + mt * 16 + l15) * 32 + kc];
#pragma unroll
        for (int nt = 0; nt < 4; ++nt)
            bfr[nt] = *(const short8*)&Bs[buf][(wn + nt * 16 + l15) * 32 + kc];
        // Swapped operands: D = C^T; lane l15 = C-row, regs = 4 consecutive cols
#pragma unroll
        for (int mt = 0; mt < 4; ++mt)
#pragma unroll
            for (int nt = 0; nt < 4; ++nt)
                acc[mt][nt] = __builtin_amdgcn_mfma_f32_16x16x32_bf16(
                    bfr[nt], a[mt], acc[mt][nt], 0, 0, 0);
        __syncthreads();  // drains this iter's stage -> buf^1 ready
    }

    // Epilogue (C^T layout): row = wm+mt*16+l15, cols = wn+nt*16+kq*4..+3
    u16* __restrict__ Cbase = (col0 < split) ? Cl : Cr;
    const int cadj = (col0 < split) ? col0 : (col0 - split);
#pragma unroll
    for (int mt = 0; mt < 4; ++mt) {
        int row = row0 + wm + mt * 16 + l15;
        if (row >= M) continue;
#pragma unroll
        for (int nt = 0; nt < 4; ++nt) {
            int c0 = cadj + wn + nt * 16 + kq * 4;
            uint2 o;
            o.x = (u32)f32_to_bf16(acc[mt][nt][0]) |
                  ((u32)f32_to_bf16(acc[mt][nt][1]) << 16);
            o.y = (u32)f32_to_bf16(acc[mt][nt][2]) |
                  ((u32)f32_to_bf16(acc[mt][nt][3]) << 16);
            *(uint2*)(Cbase + (size_t)row * split + c0) = o;
        }
    }
}

// h[node] = relu(mean(Yl[src]) + Yr[node] + bias), D=512 bf16.
// One wave per node; lane covers 8 cols (uint4).
__global__ __launch_bounds__(256) void gather_add_relu512(
    const u16* __restrict__ Yl, const u16* __restrict__ Yr,
    const float* __restrict__ bias,
    const int* __restrict__ row_start, const int* __restrict__ csr_src,
    u16* __restrict__ h, int M) {
    int node = (blockIdx.x * 256 + threadIdx.x) >> 6;
    int lane = threadIdx.x & 63;
    if (node >= M) return;
    int beg = row_start[node], end = row_start[node + 1];
    float a[8] = {0.f, 0.f, 0.f, 0.f, 0.f, 0.f, 0.f, 0.f};
    for (int c = beg; c < end; c += 64) {
        int nb = min(64, end - c);
        int eid = (lane < nb) ? csr_src[c + lane] : 0;
        for (int i = 0; i < nb; ++i) {
            int s = __shfl(eid, i);
            uint4 v = ((const uint4*)(Yl + (size_t)s * 512))[lane];
            a[0] += bf16_to_f32(v.x & 0xffffu); a[1] += bf16_to_f32(v.x >> 16);
            a[2] += bf16_to_f32(v.y & 0xffffu); a[3] += bf16_to_f32(v.y >> 16);
            a[4] += bf16_to_f32(v.z & 0xffffu); a[5] += bf16_to_f32(v.z >> 16);
            a[6] += bf16_to_f32(v.w & 0xffffu); a[7] += bf16_to_f32(v.w >> 16);
        }
    }
    float inv = 1.0f / fmaxf((float)(end - beg), 1.0f);
    uint4 yr = ((const uint4*)(Yr + (size_t)node * 512))[lane];
    float4 b0 = ((const float4*)bias)[lane * 2];
    float4 b1 = ((const float4*)bias)[lane * 2 + 1];
    float v0 = fmaxf(a[0] * inv + bf16_to_f32(yr.x & 0xffffu) + b0.x, 0.f);
    float v1 = fmaxf(a[1] * inv + bf16_to_f32(yr.x >> 16)     + b0.y, 0.f);
    float v2 = fmaxf(a[2] * inv + bf16_to_f32(yr.y & 0xffffu) + b0.z, 0.f);
    float v3 = fmaxf(a[3] * inv + bf16_to_f32(yr.y >> 16)     + b0.w, 0.f);
    float v4 = fmaxf(a[4] * inv + bf16_to_f32(yr.z & 0xffffu) + b1.x, 0.f);
    float v5 = fmaxf(a[5] * inv + bf16_to_f32(yr.z >> 16)     + b1.y, 0.f);
    float v6 = fmaxf(a[6] * inv + bf16_to_f32(yr.w & 0xffffu) + b1.z, 0.f);
    float v7 = fmaxf(a[7] * inv + bf16_to_f32(yr.w >> 16)     + b1.w, 0.f);
    uint4 o;
    o.x = (u32)f32_to_bf16(v0) | ((u32)f32_to_bf16(v1) << 16);
    o.y = (u32)f32_to_bf16(v2) | ((u32)f32_to_bf16(v3) << 16);
    o.z = (u32)f32_to_bf16(v4) | ((u32)f32_to_bf16(v5) << 16);
    o.w = (u32)f32_to_bf16(v6) | ((u32)f32_to_bf16(v7) << 16);
    ((uint4*)(h + (size_t)node * 512))[lane] = o;
}

// out[node] = log_softmax(mean(Yl[src]) + Yr[node] + bias), D=128, f32 out.
// 16 lanes per node (4 nodes/wave); lane covers 8 cols.
__global__ __launch_bounds__(256) void gather_add_lsm128(
    const u16* __restrict__ Yl, const u16* __restrict__ Yr,
    const float* __restrict__ bias,
    const int* __restrict__ row_start, const int* __restrict__ csr_src,
    float* __restrict__ out, int M) {
    int node = blockIdx.x * 16 + (threadIdx.x >> 4);
    int lane = threadIdx.x & 63;
    int li = lane & 15;
    int gbase = lane & 48;      // group base lane within wave
    if (node >= M) return;
    int beg = row_start[node], end = row_start[node + 1];
    float a[8] = {0.f, 0.f, 0.f, 0.f, 0.f, 0.f, 0.f, 0.f};
    for (int c = beg; c < end; c += 16) {
        int nb = min(16, end - c);
        int eid = (li < nb) ? csr_src[c + li] : 0;
        for (int i = 0; i < nb; ++i) {
            int s = __shfl(eid, gbase + i);
            uint4 v = ((const uint4*)(Yl + (size_t)s * 128))[li];
            a[0] += bf16_to_f32(v.x & 0xffffu); a[1] += bf16_to_f32(v.x >> 16);
            a[2] += bf16_to_f32(v.y & 0xffffu); a[3] += bf16_to_f32(v.y >> 16);
            a[4] += bf16_to_f32(v.z & 0xffffu); a[5] += bf16_to_f32(v.z >> 16);
            a[6] += bf16_to_f32(v.w & 0xffffu); a[7] += bf16_to_f32(v.w >> 16);
        }
    }
    float inv = 1.0f / fmaxf((float)(end - beg), 1.0f);
    uint4 yr = ((const uint4*)(Yr + (size_t)node * 128))[li];
    float4 b0 = ((const float4*)bias)[li * 2];
    float4 b1 = ((const float4*)bias)[li * 2 + 1];
    float v[8];
    v[0] = a[0] * inv + bf16_to_f32(yr.x & 0xffffu) + b0.x;
    v[1] = a[1] * inv + bf16_to_f32(yr.x >> 16)     + b0.y;
    v[2] = a[2] * inv + bf16_to_f32(yr.y & 0xffffu) + b0.z;
    v[3] = a[3] * inv + bf16_to_f32(yr.y >> 16)     + b0.w;
    v[4] = a[4] * inv + bf16_to_f32(yr.z & 0xffffu) + b1.x;
    v[5] = a[5] * inv + bf16_to_f32(yr.z >> 16)     + b1.y;
    v[6] = a[6] * inv + bf16_to_f32(yr.w & 0xffffu) + b1.z;
    v[7] = a[7] * inv + bf16_to_f32(yr.w >> 16)     + b1.w;
    float m = v[0];
#pragma unroll
    for (int j = 1; j < 8; ++j) m = fmaxf(m, v[j]);
#pragma unroll
    for (int off = 1; off < 16; off <<= 1) m = fmaxf(m, __shfl_xor(m, off));
    float s = 0.f;
#pragma unroll
    for (int j = 0; j < 8; ++j) s += expf(v[j] - m);
#pragma unroll
    for (int off = 1; off < 16; off <<= 1) s += __shfl_xor(s, off);
    float ls = m + logf(s);
    float* p = out + (size_t)node * 128 + li * 8;
    *(float4*)p       = make_float4(v[0] - ls, v[1] - ls, v[2] - ls, v[3] - ls);
    *(float4*)(p + 4) = make_float4(v[4] - ls, v[5] - ls, v[6] - ls, v[7] - ls);
}

extern "C" void kernel_launch(void* const* d_in, const int* in_sizes, int n_in,
                              void* d_out, int out_size, void* d_ws, size_t ws_size,
                              hipStream_t stream) {
    const float* x    = (const float*)d_in[0];
    const int*   ei   = (const int*)d_in[1];
    const float* W1_l = (const float*)d_in[2];
    const float* b1   = (const float*)d_in[3];
    const float* W1_r = (const float*)d_in[4];
    const float* W2_l = (const float*)d_in[5];
    const float* b2   = (const float*)d_in[6];
    const float* W2_r = (const float*)d_in[7];
    const float* W3_l = (const float*)d_in[8];
    const float* b3   = (const float*)d_in[9];
    const float* W3_r = (const float*)d_in[10];
    float* out = (float*)d_out;

    const int* src = ei;
    const int* dst = ei + N_EDGES;

    // Workspace layout (bytes from base):
    char* base = (char*)d_ws;
    int* row_start = (int*)(base);                    // 50052 ints
    int* cursor    = (int*)(base + 200208);           // 50052 ints
    int* bsums     = (int*)(base + 400416);           // 512 ints
    int* csr_src   = (int*)(base + 402464);           // 400000 ints -> end 2002464
    u16* xb  = (u16*)(base + 2002464);                // [M][512] bf16
    u16* h1b = (u16*)(base + 53202464);               // [M][512]
    u16* h2b = (u16*)(base + 104402464);              // [M][512]
    u16* Yl  = (u16*)(base + 155602464);              // [M][512] (layer3: [M][128])
    u16* Yr  = (u16*)(base + 206802464);              // [M][512] (layer3: [M][128])
    u16* w1T = (u16*)(base + 258002464);              // [1024][512]
    u16* w2T = (u16*)(base + 259051040);              // [1024][512]
    u16* w3T = (u16*)(base + 260099616);              // [256][512] -> end 260361760

    const int E = N_EDGES, M = N_NODES;
    const int nblk = (M + 255) / 256;

    // ---- CSR build ----
    zero4_kernel<<<(25154 + 255) / 256, 256, 0, stream>>>((float4*)d_ws, 25154);
    hist_kernel<<<(E + 255) / 256, 256, 0, stream>>>(dst, row_start, E);
    scan_reduce<<<nblk, 256, 0, stream>>>(row_start, bsums, M);
    scan_sums<<<1, 256, 0, stream>>>(bsums, nblk);
    scan_final<<<nblk, 256, 0, stream>>>(row_start, bsums, M);
    fill_kernel<<<(E + 255) / 256, 256, 0, stream>>>(src, dst, row_start, cursor,
                                                     csr_src, E);

    // ---- conversions: x -> bf16; weights -> WT [N][K] bf16, l/r concat ----
    convert_bf16<<<(3200000 + 255) / 256, 256, 0, stream>>>(x, xb, 3200000);
    transpose_w<<<dim3(16, 16), 256, 0, stream>>>(W1_l, w1T, 512, 512);
    transpose_w<<<dim3(16, 16), 256, 0, stream>>>(W1_r, w1T + 512 * 512, 512, 512);
    transpose_w<<<dim3(16, 16), 256, 0, stream>>>(W2_l, w2T, 512, 512);
    transpose_w<<<dim3(16, 16), 256, 0, stream>>>(W2_r, w2T + 512 * 512, 512, 512);
    transpose_w<<<dim3(4, 16), 256, 0, stream>>>(W3_l, w3T, 512, 128);
    transpose_w<<<dim3(4, 16), 256, 0, stream>>>(W3_r, w3T + 128 * 512, 512, 128);

    const int nStrips = (M + 127) / 128;                 // 391
    const int grid8 = ((nStrips + 7) / 8) * 64;          // 3136 (nCols=8)
    const int grid2 = ((nStrips + 7) / 8) * 16;          // 784  (nCols=2)
    const int gblocks = (M * 64 + 255) / 256;            // wave/node
    const int g16blocks = (M + 15) / 16;                 // 16 lanes/node

    // ---- layer 1: Y = x@[W1_l|W1_r]; h1 = relu(gather(Yl)+Yr+b1) ----
    gemm_bf16<<<grid8, 256, 0, stream>>>(xb, w1T, Yl, Yr, M, 512, nStrips, 8);
    gather_add_relu512<<<gblocks, 256, 0, stream>>>(Yl, Yr, b1, row_start,
                                                    csr_src, h1b, M);
    // ---- layer 2 ----
    gemm_bf16<<<grid8, 256, 0, stream>>>(h1b, w2T, Yl, Yr, M, 512, nStrips, 8);
    gather_add_relu512<<<gblocks, 256, 0, stream>>>(Yl, Yr, b2, row_start,
                                                    csr_src, h2b, M);
    // ---- layer 3: Y3 = h2@[W3_l|W3_r]; out = lsm(gather(Y3l)+Y3r+b3) ----
    gemm_bf16<<<grid2, 256, 0, stream>>>(h2b, w3T, Yl, Yr, M, 128, nStrips, 2);
    gather_add_lsm128<<<g16blocks, 256, 0, stream>>>(Yl, Yr, b3, row_start,
                                                     csr_src, out, M);
}

// Round 2
// 655.906 us; speedup vs baseline: 1.0093x; 1.0014x over previous
//
#include <hip/hip_runtime.h>
#include <hip/hip_bf16.h>

// GraphSAGE 3-layer, N=50000 nodes, E=400000 edges, dims 512->512->512->128.
// Round 9 -> 10:
//  GEMM goes 256 -> 512 threads (8 waves/block, 2x4 wave grid, each wave owns
//  a 64x32 output sub-tile, acc[4][2] = 32 AGPR/wave). Same 128x128 tile, same
//  2-phase template, same source-swizzled global_load_lds staging (now 2 loads
//  per thread instead of 4). Halved per-wave register footprint -> 16-24
//  resident waves/CU (up from 12): the 2-phase structure hides its per-iter
//  vmcnt(0) HBM-latency drain ONLY via cross-block wave overlap (m114), and at
//  12 waves/CU the barrier-locked blocks convoy (measured ~4000 cy/iter vs
//  ~310 cy of MFMA).

#define N_NODES 50000
#define N_EDGES 400000

typedef unsigned short u16;
typedef unsigned int u32;
typedef __attribute__((ext_vector_type(8))) short short8;
typedef __attribute__((ext_vector_type(4))) float floatx4;

#define ASYNC16(g, l)                                                      \
    __builtin_amdgcn_global_load_lds(                                      \
        (const __attribute__((address_space(1))) void*)(g),                \
        (__attribute__((address_space(3))) void*)(l), 16, 0, 0)

__device__ __forceinline__ u16 f32_to_bf16(float f) {
    u32 u = __float_as_uint(f);
    u32 r = 0x7FFFu + ((u >> 16) & 1u);
    return (u16)((u + r) >> 16);
}
__device__ __forceinline__ float bf16_to_f32(u32 lo16) {
    return __uint_as_float(lo16 << 16);
}

__global__ __launch_bounds__(256) void zero4_kernel(float4* __restrict__ p, int n4) {
    int i = blockIdx.x * 256 + threadIdx.x;
    if (i < n4) p[i] = make_float4(0.f, 0.f, 0.f, 0.f);
}

__global__ __launch_bounds__(256) void hist_kernel(const int* __restrict__ dst,
                                                   int* __restrict__ deg, int E) {
    int e = blockIdx.x * 256 + threadIdx.x;
    if (e < E) atomicAdd(&deg[dst[e]], 1);
}

__global__ __launch_bounds__(256) void scan_reduce(const int* __restrict__ v,
                                                   int* __restrict__ bsums, int n) {
    __shared__ int sh[256];
    int i = blockIdx.x * 256 + threadIdx.x;
    sh[threadIdx.x] = (i < n) ? v[i] : 0;
    __syncthreads();
    for (int off = 128; off > 0; off >>= 1) {
        if (threadIdx.x < off) sh[threadIdx.x] += sh[threadIdx.x + off];
        __syncthreads();
    }
    if (threadIdx.x == 0) bsums[blockIdx.x] = sh[0];
}

__global__ __launch_bounds__(256) void scan_sums(int* __restrict__ bsums, int nb) {
    __shared__ int sh[256];
    int t = threadIdx.x;
    int val = (t < nb) ? bsums[t] : 0;
    sh[t] = val;
    __syncthreads();
    for (int off = 1; off < 256; off <<= 1) {
        int v = (t >= off) ? sh[t - off] : 0;
        __syncthreads();
        sh[t] += v;
        __syncthreads();
    }
    if (t < nb) bsums[t] = sh[t] - val;
}

__global__ __launch_bounds__(256) void scan_final(int* __restrict__ v,
                                                  const int* __restrict__ bsums, int n) {
    __shared__ int sh[256];
    int t = threadIdx.x;
    int i = blockIdx.x * 256 + t;
    int val = (i < n) ? v[i] : 0;
    sh[t] = val;
    __syncthreads();
    for (int off = 1; off < 256; off <<= 1) {
        int x = (t >= off) ? sh[t - off] : 0;
        __syncthreads();
        sh[t] += x;
        __syncthreads();
    }
    int excl = sh[t] - val + bsums[blockIdx.x];
    if (i < n) v[i] = excl;
    if (i == n - 1) v[n] = excl + val;
}

__global__ __launch_bounds__(256) void fill_kernel(const int* __restrict__ src,
                                                   const int* __restrict__ dst,
                                                   const int* __restrict__ row_start,
                                                   int* __restrict__ cursor,
                                                   int* __restrict__ csr_src, int E) {
    int e = blockIdx.x * 256 + threadIdx.x;
    if (e < E) {
        int d = dst[e];
        int pos = row_start[d] + atomicAdd(&cursor[d], 1);
        csr_src[pos] = src[e];
    }
}

// f32 [n8*8] -> bf16, 8 elems/thread
__global__ __launch_bounds__(256) void convert_bf16(const float* __restrict__ in,
                                                    u16* __restrict__ out, int n8) {
    int i = blockIdx.x * 256 + threadIdx.x;
    if (i >= n8) return;
    const float4* p = (const float4*)in + (size_t)i * 2;
    float4 v0 = p[0], v1 = p[1];
    uint4 o;
    o.x = (u32)f32_to_bf16(v0.x) | ((u32)f32_to_bf16(v0.y) << 16);
    o.y = (u32)f32_to_bf16(v0.z) | ((u32)f32_to_bf16(v0.w) << 16);
    o.z = (u32)f32_to_bf16(v1.x) | ((u32)f32_to_bf16(v1.y) << 16);
    o.w = (u32)f32_to_bf16(v1.z) | ((u32)f32_to_bf16(v1.w) << 16);
    ((uint4*)out)[i] = o;
}

// W [K][N] f32 -> WT [N][K] bf16, 32x32 tiles
__global__ __launch_bounds__(256) void transpose_w(const float* __restrict__ W,
                                                   u16* __restrict__ WT,
                                                   int K, int N) {
    __shared__ float t[32][33];
    int n0 = blockIdx.x * 32, k0 = blockIdx.y * 32;
    int c = threadIdx.x & 31, r0 = threadIdx.x >> 5;
    for (int r = r0; r < 32; r += 8)
        t[r][c] = W[(size_t)(k0 + r) * N + n0 + c];
    __syncthreads();
    for (int r = r0; r < 32; r += 8)
        WT[(size_t)(n0 + r) * K + k0 + c] = f32_to_bf16(t[c][r]);
}

// C = A @ BT' (BT stored [N][512], k-contig), single pass K=512, bf16 out.
// 128x128 tile, 512 threads (8 waves, 2Mx4N), dbuf LDS, global_load_lds
// staging (lane-linear dest, source-swizzled), 1 barrier/iter,
// swapped-operand MFMA. Wave w: wm=(w>>2)*64, wn=(w&3)*32, acc[4][2].
// Output split: cols < split -> Cl (row stride split), else Cr (col-split).
__global__ __launch_bounds__(512) void gemm_bf16(
    const u16* __restrict__ A, const u16* __restrict__ BT,
    u16* __restrict__ Cl, u16* __restrict__ Cr,
    int M, int split, int nStrips, int nCols) {
    __shared__ u16 As[2][4096];  // 128 rows x 32 u16 (64B), lane-linear
    __shared__ u16 Bs[2][4096];

    const int grp = 8 * nCols;
    int b = blockIdx.x;
    int strip = (b / grp) * 8 + (b & 7);   // col-tiles of a strip share b%8 -> XCD
    int colt = (b % grp) >> 3;
    if (strip >= nStrips) return;
    const int row0 = strip * 128, col0 = colt * 128;

    const int t = threadIdx.x;
    const int w = t >> 6, lane = t & 63;
    const int wm = (w >> 2) * 64, wn = (w & 3) * 32;
    const int l15 = lane & 15, kq = lane >> 4;
    const int swz = (l15 >> 1) & 3;        // fragment-read swizzle bits

    floatx4 acc[4][2];
#pragma unroll
    for (int i = 0; i < 4; ++i)
#pragma unroll
        for (int j = 0; j < 2; ++j) acc[i][j] = floatx4{0.f, 0.f, 0.f, 0.f};

    // Staging geometry: 512 threads x 16B = one 8KB half (A or B) each.
    // Thread t -> row sr = t>>2 (0..127), chunk sc = t&3. LDS dest is
    // lane-linear per wave: byte off = (64w+lane)*16 = w*1024 + lane*16.
    // Bank swizzle lives in the GLOBAL source: position sc receives global
    // chunk sc^swzS; reader fetches logical chunk kq at position kq^swz.
    const int sr = t >> 2;
    const int sc = t & 3;
    const int swzS = (sr >> 1) & 3;
    const size_t aA0 = (size_t)min(row0 + sr, M - 1) * 512 + (sc ^ swzS) * 8;
    const size_t aB0 = (size_t)(col0 + sr) * 512 + (sc ^ swzS) * 8;
    const int d0 = w * 512;        // u16 index: wave-uniform LDS dest

    auto stage = [&](int it, int buf) {
        const int eff = it * 32;
        ASYNC16(A + aA0 + eff, &As[buf][d0]);
        ASYNC16(BT + aB0 + eff, &Bs[buf][d0]);
    };

    stage(0, 0);
    __syncthreads();  // vmcnt(0) drain: buf0 ready
    for (int it = 0; it < 16; ++it) {
        const int buf = it & 1;
        if (it + 1 < 16) stage(it + 1, buf ^ 1);  // in flight across the MFMAs

        const int kc = (kq ^ swz) * 8;      // swizzled chunk for this lane
        short8 a[4], bfr[2];
#pragma unroll
        for (int mt = 0; mt < 4; ++mt)
            a[mt] = *(const short8*)&As[buf][(wm + mt * 16 + l15) * 32 + kc];
#pragma unroll
        for (int nt = 0; nt < 2; ++nt)
            bfr[nt] = *(const short8*)&Bs[buf][(wn + nt * 16 + l15) * 32 + kc];
        // Swapped operands: D = C^T; lane l15 = C-row, regs = 4 consecutive cols
#pragma unroll
        for (int mt = 0; mt < 4; ++mt)
#pragma unroll
            for (int nt = 0; nt < 2; ++nt)
                acc[mt][nt] = __builtin_amdgcn_mfma_f32_16x16x32_bf16(
                    bfr[nt], a[mt], acc[mt][nt], 0, 0, 0);
        __syncthreads();  // drains this iter's stage -> buf^1 ready
    }

    // Epilogue (C^T layout): row = wm+mt*16+l15, cols = wn+nt*16+kq*4..+3
    u16* __restrict__ Cbase = (col0 < split) ? Cl : Cr;
    const int cadj = (col0 < split) ? col0 : (col0 - split);
#pragma unroll
    for (int mt = 0; mt < 4; ++mt) {
        int row = row0 + wm + mt * 16 + l15;
        if (row >= M) continue;
#pragma unroll
        for (int nt = 0; nt < 2; ++nt) {
            int c0 = cadj + wn + nt * 16 + kq * 4;
            uint2 o;
            o.x = (u32)f32_to_bf16(acc[mt][nt][0]) |
                  ((u32)f32_to_bf16(acc[mt][nt][1]) << 16);
            o.y = (u32)f32_to_bf16(acc[mt][nt][2]) |
                  ((u32)f32_to_bf16(acc[mt][nt][3]) << 16);
            *(uint2*)(Cbase + (size_t)row * split + c0) = o;
        }
    }
}

// h[node] = relu(mean(Yl[src]) + Yr[node] + bias), D=512 bf16.
// One wave per node; lane covers 8 cols (uint4).
__global__ __launch_bounds__(256) void gather_add_relu512(
    const u16* __restrict__ Yl, const u16* __restrict__ Yr,
    const float* __restrict__ bias,
    const int* __restrict__ row_start, const int* __restrict__ csr_src,
    u16* __restrict__ h, int M) {
    int node = (blockIdx.x * 256 + threadIdx.x) >> 6;
    int lane = threadIdx.x & 63;
    if (node >= M) return;
    int beg = row_start[node], end = row_start[node + 1];
    float a[8] = {0.f, 0.f, 0.f, 0.f, 0.f, 0.f, 0.f, 0.f};
    for (int c = beg; c < end; c += 64) {
        int nb = min(64, end - c);
        int eid = (lane < nb) ? csr_src[c + lane] : 0;
        for (int i = 0; i < nb; ++i) {
            int s = __shfl(eid, i);
            uint4 v = ((const uint4*)(Yl + (size_t)s * 512))[lane];
            a[0] += bf16_to_f32(v.x & 0xffffu); a[1] += bf16_to_f32(v.x >> 16);
            a[2] += bf16_to_f32(v.y & 0xffffu); a[3] += bf16_to_f32(v.y >> 16);
            a[4] += bf16_to_f32(v.z & 0xffffu); a[5] += bf16_to_f32(v.z >> 16);
            a[6] += bf16_to_f32(v.w & 0xffffu); a[7] += bf16_to_f32(v.w >> 16);
        }
    }
    float inv = 1.0f / fmaxf((float)(end - beg), 1.0f);
    uint4 yr = ((const uint4*)(Yr + (size_t)node * 512))[lane];
    float4 b0 = ((const float4*)bias)[lane * 2];
    float4 b1 = ((const float4*)bias)[lane * 2 + 1];
    float v0 = fmaxf(a[0] * inv + bf16_to_f32(yr.x & 0xffffu) + b0.x, 0.f);
    float v1 = fmaxf(a[1] * inv + bf16_to_f32(yr.x >> 16)     + b0.y, 0.f);
    float v2 = fmaxf(a[2] * inv + bf16_to_f32(yr.y & 0xffffu) + b0.z, 0.f);
    float v3 = fmaxf(a[3] * inv + bf16_to_f32(yr.y >> 16)     + b0.w, 0.f);
    float v4 = fmaxf(a[4] * inv + bf16_to_f32(yr.z & 0xffffu) + b1.x, 0.f);
    float v5 = fmaxf(a[5] * inv + bf16_to_f32(yr.z >> 16)     + b1.y, 0.f);
    float v6 = fmaxf(a[6] * inv + bf16_to_f32(yr.w & 0xffffu) + b1.z, 0.f);
    float v7 = fmaxf(a[7] * inv + bf16_to_f32(yr.w >> 16)     + b1.w, 0.f);
    uint4 o;
    o.x = (u32)f32_to_bf16(v0) | ((u32)f32_to_bf16(v1) << 16);
    o.y = (u32)f32_to_bf16(v2) | ((u32)f32_to_bf16(v3) << 16);
    o.z = (u32)f32_to_bf16(v4) | ((u32)f32_to_bf16(v5) << 16);
    o.w = (u32)f32_to_bf16(v6) | ((u32)f32_to_bf16(v7) << 16);
    ((uint4*)(h + (size_t)node * 512))[lane] = o;
}

// out[node] = log_softmax(mean(Yl[src]) + Yr[node] + bias), D=128, f32 out.
// 16 lanes per node (4 nodes/wave); lane covers 8 cols.
__global__ __launch_bounds__(256) void gather_add_lsm128(
    const u16* __restrict__ Yl, const u16* __restrict__ Yr,
    const float* __restrict__ bias,
    const int* __restrict__ row_start, const int* __restrict__ csr_src,
    float* __restrict__ out, int M) {
    int node = blockIdx.x * 16 + (threadIdx.x >> 4);
    int lane = threadIdx.x & 63;
    int li = lane & 15;
    int gbase = lane & 48;      // group base lane within wave
    if (node >= M) return;
    int beg = row_start[node], end = row_start[node + 1];
    float a[8] = {0.f, 0.f, 0.f, 0.f, 0.f, 0.f, 0.f, 0.f};
    for (int c = beg; c < end; c += 16) {
        int nb = min(16, end - c);
        int eid = (li < nb) ? csr_src[c + li] : 0;
        for (int i = 0; i < nb; ++i) {
            int s = __shfl(eid, gbase + i);
            uint4 v = ((const uint4*)(Yl + (size_t)s * 128))[li];
            a[0] += bf16_to_f32(v.x & 0xffffu); a[1] += bf16_to_f32(v.x >> 16);
            a[2] += bf16_to_f32(v.y & 0xffffu); a[3] += bf16_to_f32(v.y >> 16);
            a[4] += bf16_to_f32(v.z & 0xffffu); a[5] += bf16_to_f32(v.z >> 16);
            a[6] += bf16_to_f32(v.w & 0xffffu); a[7] += bf16_to_f32(v.w >> 16);
        }
    }
    float inv = 1.0f / fmaxf((float)(end - beg), 1.0f);
    uint4 yr = ((const uint4*)(Yr + (size_t)node * 128))[li];
    float4 b0 = ((const float4*)bias)[li * 2];
    float4 b1 = ((const float4*)bias)[li * 2 + 1];
    float v[8];
    v[0] = a[0] * inv + bf16_to_f32(yr.x & 0xffffu) + b0.x;
    v[1] = a[1] * inv + bf16_to_f32(yr.x >> 16)     + b0.y;
    v[2] = a[2] * inv + bf16_to_f32(yr.y & 0xffffu) + b0.z;
    v[3] = a[3] * inv + bf16_to_f32(yr.y >> 16)     + b0.w;
    v[4] = a[4] * inv + bf16_to_f32(yr.z & 0xffffu) + b1.x;
    v[5] = a[5] * inv + bf16_to_f32(yr.z >> 16)     + b1.y;
    v[6] = a[6] * inv + bf16_to_f32(yr.w & 0xffffu) + b1.z;
    v[7] = a[7] * inv + bf16_to_f32(yr.w >> 16)     + b1.w;
    float m = v[0];
#pragma unroll
    for (int j = 1; j < 8; ++j) m = fmaxf(m, v[j]);
#pragma unroll
    for (int off = 1; off < 16; off <<= 1) m = fmaxf(m, __shfl_xor(m, off));
    float s = 0.f;
#pragma unroll
    for (int j = 0; j < 8; ++j) s += expf(v[j] - m);
#pragma unroll
    for (int off = 1; off < 16; off <<= 1) s += __shfl_xor(s, off);
    float ls = m + logf(s);
    float* p = out + (size_t)node * 128 + li * 8;
    *(float4*)p       = make_float4(v[0] - ls, v[1] - ls, v[2] - ls, v[3] - ls);
    *(float4*)(p + 4) = make_float4(v[4] - ls, v[5] - ls, v[6] - ls, v[7] - ls);
}

extern "C" void kernel_launch(void* const* d_in, const int* in_sizes, int n_in,
                              void* d_out, int out_size, void* d_ws, size_t ws_size,
                              hipStream_t stream) {
    const float* x    = (const float*)d_in[0];
    const int*   ei   = (const int*)d_in[1];
    const float* W1_l = (const float*)d_in[2];
    const float* b1   = (const float*)d_in[3];
    const float* W1_r = (const float*)d_in[4];
    const float* W2_l = (const float*)d_in[5];
    const float* b2   = (const float*)d_in[6];
    const float* W2_r = (const float*)d_in[7];
    const float* W3_l = (const float*)d_in[8];
    const float* b3   = (const float*)d_in[9];
    const float* W3_r = (const float*)d_in[10];
    float* out = (float*)d_out;

    const int* src = ei;
    const int* dst = ei + N_EDGES;

    // Workspace layout (bytes from base):
    char* base = (char*)d_ws;
    int* row_start = (int*)(base);                    // 50052 ints
    int* cursor    = (int*)(base + 200208);           // 50052 ints
    int* bsums     = (int*)(base + 400416);           // 512 ints
    int* csr_src   = (int*)(base + 402464);           // 400000 ints -> end 2002464
    u16* xb  = (u16*)(base + 2002464);                // [M][512] bf16
    u16* h1b = (u16*)(base + 53202464);               // [M][512]
    u16* h2b = (u16*)(base + 104402464);              // [M][512]
    u16* Yl  = (u16*)(base + 155602464);              // [M][512] (layer3: [M][128])
    u16* Yr  = (u16*)(base + 206802464);              // [M][512] (layer3: [M][128])
    u16* w1T = (u16*)(base + 258002464);              // [1024][512]
    u16* w2T = (u16*)(base + 259051040);              // [1024][512]
    u16* w3T = (u16*)(base + 260099616);              // [256][512] -> end 260361760

    const int E = N_EDGES, M = N_NODES;
    const int nblk = (M + 255) / 256;

    // ---- CSR build ----
    zero4_kernel<<<(25154 + 255) / 256, 256, 0, stream>>>((float4*)d_ws, 25154);
    hist_kernel<<<(E + 255) / 256, 256, 0, stream>>>(dst, row_start, E);
    scan_reduce<<<nblk, 256, 0, stream>>>(row_start, bsums, M);
    scan_sums<<<1, 256, 0, stream>>>(bsums, nblk);
    scan_final<<<nblk, 256, 0, stream>>>(row_start, bsums, M);
    fill_kernel<<<(E + 255) / 256, 256, 0, stream>>>(src, dst, row_start, cursor,
                                                     csr_src, E);

    // ---- conversions: x -> bf16; weights -> WT [N][K] bf16, l/r concat ----
    convert_bf16<<<(3200000 + 255) / 256, 256, 0, stream>>>(x, xb, 3200000);
    transpose_w<<<dim3(16, 16), 256, 0, stream>>>(W1_l, w1T, 512, 512);
    transpose_w<<<dim3(16, 16), 256, 0, stream>>>(W1_r, w1T + 512 * 512, 512, 512);
    transpose_w<<<dim3(16, 16), 256, 0, stream>>>(W2_l, w2T, 512, 512);
    transpose_w<<<dim3(16, 16), 256, 0, stream>>>(W2_r, w2T + 512 * 512, 512, 512);
    transpose_w<<<dim3(4, 16), 256, 0, stream>>>(W3_l, w3T, 512, 128);
    transpose_w<<<dim3(4, 16), 256, 0, stream>>>(W3_r, w3T + 128 * 512, 512, 128);

    const int nStrips = (M + 127) / 128;                 // 391
    const int grid8 = ((nStrips + 7) / 8) * 64;          // 3136 (nCols=8)
    const int grid2 = ((nStrips + 7) / 8) * 16;          // 784  (nCols=2)
    const int gblocks = (M * 64 + 255) / 256;            // wave/node
    const int g16blocks = (M + 15) / 16;                 // 16 lanes/node

    // ---- layer 1: Y = x@[W1_l|W1_r]; h1 = relu(gather(Yl)+Yr+b1) ----
    gemm_bf16<<<grid8, 512, 0, stream>>>(xb, w1T, Yl, Yr, M, 512, nStrips, 8);
    gather_add_relu512<<<gblocks, 256, 0, stream>>>(Yl, Yr, b1, row_start,
                                                    csr_src, h1b, M);
    // ---- layer 2 ----
    gemm_bf16<<<grid8, 512, 0, stream>>>(h1b, w2T, Yl, Yr, M, 512, nStrips, 8);
    gather_add_relu512<<<gblocks, 256, 0, stream>>>(Yl, Yr, b2, row_start,
                                                    csr_src, h2b, M);
    // ---- layer 3: Y3 = h2@[W3_l|W3_r]; out = lsm(gather(Y3l)+Y3r+b3) ----
    gemm_bf16<<<grid2, 512, 0, stream>>>(h2b, w3T, Yl, Yr, M, 128, nStrips, 2);
    gather_add_lsm128<<<g16blocks, 256, 0, stream>>>(Yl, Yr, b3, row_start,
                                                     csr_src, out, M);
}